// Round 1
// baseline (5156.093 us; speedup 1.0000x reference)
//
#include <hip/hip_runtime.h>
#include <math.h>

#define HID 128
#define HEADS 4
#define CPH 32
#define NEG_SLOPE 0.2f

// ---------------- CSR build ----------------

__global__ __launch_bounds__(256) void k_zero_int(int* p, int n) {
    int i = blockIdx.x * blockDim.x + threadIdx.x;
    if (i < n) p[i] = 0;
}

__global__ __launch_bounds__(256) void k_hist(const int* __restrict__ dst, int E, int* __restrict__ counts) {
    int e = blockIdx.x * blockDim.x + threadIdx.x;
    if (e < E) atomicAdd(&counts[dst[e]], 1);
}

// Single-block exclusive scan over counts[0..N) -> rowptr[0..N]; nextp = rowptr copy.
__global__ __launch_bounds__(256) void k_scan(const int* __restrict__ counts, int N,
                                              int* __restrict__ rowptr, int* __restrict__ nextp) {
    __shared__ int buf[256];
    __shared__ int carry;
    int tid = threadIdx.x;
    if (tid == 0) carry = 0;
    __syncthreads();
    for (int base = 0; base < N; base += 256) {
        int i = base + tid;
        int v = (i < N) ? counts[i] : 0;
        buf[tid] = v;
        __syncthreads();
        // inclusive Hillis-Steele scan
        for (int off = 1; off < 256; off <<= 1) {
            int t = (tid >= off) ? buf[tid - off] : 0;
            __syncthreads();
            buf[tid] += t;
            __syncthreads();
        }
        int excl = carry + buf[tid] - v;
        if (i < N) { rowptr[i] = excl; nextp[i] = excl; }
        __syncthreads();
        if (tid == 255) carry += buf[255];
        __syncthreads();
    }
    if (tid == 0) rowptr[N] = carry;
}

__global__ __launch_bounds__(256) void k_scatter(const int* __restrict__ src, const int* __restrict__ dst, int E,
                                                 int* __restrict__ nextp,
                                                 int* __restrict__ csr_src, int* __restrict__ csr_dst) {
    int e = blockIdx.x * blockDim.x + threadIdx.x;
    if (e < E) {
        int d = dst[e];
        int pos = atomicAdd(&nextp[d], 1);
        csr_src[pos] = src[e];
        csr_dst[pos] = d;
    }
}

// ---------------- Embedding: x = relu(nf @ W_emb.T + b_emb) ----------------

__global__ __launch_bounds__(128) void k_embed(const float* __restrict__ nf, const float* __restrict__ W,
                                               const float* __restrict__ b, float* __restrict__ x, int N) {
    __shared__ float f[11];
    int n = blockIdx.x;
    int h = threadIdx.x;
    if (h < 11) f[h] = nf[(size_t)n * 11 + h];
    __syncthreads();
    float acc = b[h];
    #pragma unroll
    for (int k = 0; k < 11; k++) acc += f[k] * W[h * 11 + k];
    x[(size_t)n * HID + h] = fmaxf(acc, 0.f);
}

// ---------------- Linear: xl = x@Wl.T+bl ; xr = x@Wr.T+br ----------------

__global__ __launch_bounds__(128) void k_linear(const float* __restrict__ x,
                                                const float* __restrict__ Wl, const float* __restrict__ bl,
                                                const float* __restrict__ Wr, const float* __restrict__ br,
                                                float* __restrict__ xl, float* __restrict__ xr, int N) {
    __shared__ float xs[HID];
    int n = blockIdx.x;
    int h = threadIdx.x;
    xs[h] = x[(size_t)n * HID + h];
    __syncthreads();
    const float4* xs4 = (const float4*)xs;
    const float4* wl4 = (const float4*)(Wl + (size_t)h * HID);
    const float4* wr4 = (const float4*)(Wr + (size_t)h * HID);
    float accl = bl[h], accr = br[h];
    #pragma unroll 8
    for (int k = 0; k < HID / 4; k++) {
        float4 xv = xs4[k];
        float4 wv = wl4[k];
        accl += xv.x * wv.x + xv.y * wv.y + xv.z * wv.z + xv.w * wv.w;
        float4 wv2 = wr4[k];
        accr += xv.x * wv2.x + xv.y * wv2.y + xv.z * wv2.z + xv.w * wv2.w;
    }
    xl[(size_t)n * HID + h] = accl;
    xr[(size_t)n * HID + h] = accr;
}

// ---------------- Edge logits (CSR order): leaky_relu(xl[src]+xr[dst]) . att ----------------

__global__ __launch_bounds__(256) void k_logits(const float* __restrict__ xl, const float* __restrict__ xr,
                                                const int* __restrict__ csr_src, const int* __restrict__ csr_dst,
                                                const float* __restrict__ att, float* __restrict__ logits, int E) {
    int t = blockIdx.x * blockDim.x + threadIdx.x;
    if (t >= E * HEADS) return;
    int j = t >> 2;
    int h = t & 3;
    int s = csr_src[j], d = csr_dst[j];
    const float4* a4 = (const float4*)(xl + (size_t)s * HID + h * CPH);
    const float4* b4 = (const float4*)(xr + (size_t)d * HID + h * CPH);
    const float4* t4 = (const float4*)(att + h * CPH);
    float acc = 0.f;
    #pragma unroll
    for (int q = 0; q < CPH / 4; q++) {
        float4 av = a4[q], bv = b4[q], tv = t4[q];
        float e0 = av.x + bv.x, e1 = av.y + bv.y, e2 = av.z + bv.z, e3 = av.w + bv.w;
        e0 = e0 > 0.f ? e0 : NEG_SLOPE * e0;
        e1 = e1 > 0.f ? e1 : NEG_SLOPE * e1;
        e2 = e2 > 0.f ? e2 : NEG_SLOPE * e2;
        e3 = e3 > 0.f ? e3 : NEG_SLOPE * e3;
        acc += e0 * tv.x + e1 * tv.y + e2 * tv.z + e3 * tv.w;
    }
    logits[t] = acc;
}

// ---------------- Per-node fused softmax + aggregate + bias + relu + residual ----------------

__global__ __launch_bounds__(128) void k_aggregate(const float* __restrict__ xl, const float* __restrict__ logits,
                                                   const int* __restrict__ rowptr, const int* __restrict__ csr_src,
                                                   const float* __restrict__ bias, const float* __restrict__ x_res,
                                                   float* __restrict__ out, int add_res, int N) {
    int n = blockIdx.x;
    int tid = threadIdx.x;
    int h = tid >> 5;
    int c = tid & 31;
    int s0 = rowptr[n], s1 = rowptr[n + 1];
    float mx = -INFINITY;
    for (int j = s0; j < s1; j++) mx = fmaxf(mx, logits[j * 4 + h]);
    float denom = 0.f, acc = 0.f;
    for (int j = s0; j < s1; j++) {
        float p = __expf(logits[j * 4 + h] - mx);
        denom += p;
        acc += p * xl[(size_t)csr_src[j] * HID + h * CPH + c];
    }
    float v = (denom > 0.f) ? acc / denom : 0.f;
    v += bias[tid];
    v = fmaxf(v, 0.f);
    if (add_res) v += x_res[(size_t)n * HID + tid];
    out[(size_t)n * HID + tid] = v;
}

// ---------------- Graph readout: mean + max over nodes ----------------

__global__ __launch_bounds__(128) void k_reduce1(const float* __restrict__ x, int N,
                                                 float* __restrict__ psum, float* __restrict__ pmax) {
    int b = blockIdx.x;
    int h = threadIdx.x;
    int per = (N + gridDim.x - 1) / gridDim.x;
    int n0 = b * per, n1 = min(N, n0 + per);
    float s = 0.f, m = -INFINITY;
    for (int n = n0; n < n1; n++) {
        float v = x[(size_t)n * HID + h];
        s += v;
        m = fmaxf(m, v);
    }
    psum[b * HID + h] = s;
    pmax[b * HID + h] = m;
}

__global__ __launch_bounds__(128) void k_reduce2(const float* __restrict__ psum, const float* __restrict__ pmax,
                                                 int nb, float* __restrict__ out, float invN) {
    int h = threadIdx.x;
    float s = 0.f, m = -INFINITY;
    for (int b = 0; b < nb; b++) {
        s += psum[b * HID + h];
        m = fmaxf(m, pmax[b * HID + h]);
    }
    out[h] = s * invN;
    out[HID + h] = m;
}

// ---------------- Launch ----------------

extern "C" void kernel_launch(void* const* d_in, const int* in_sizes, int n_in,
                              void* d_out, int out_size, void* d_ws, size_t ws_size,
                              hipStream_t stream) {
    const float* nf    = (const float*)d_in[0];
    const int*   ei    = (const int*)d_in[1];
    const float* W_emb = (const float*)d_in[3];
    const float* b_emb = (const float*)d_in[4];
    const float* Wl    = (const float*)d_in[5];
    const float* bl    = (const float*)d_in[6];
    const float* Wr    = (const float*)d_in[7];
    const float* br    = (const float*)d_in[8];
    const float* att   = (const float*)d_in[9];
    const float* bias  = (const float*)d_in[10];

    const int N = in_sizes[0] / 11;
    const int E = in_sizes[1] / 2;
    const int* src = ei;
    const int* dst = ei + E;

    float* out  = (float*)d_out;
    float* xout = out + 2 * HID;  // final per-node features live directly in d_out

    // workspace carve-up
    char* w = (char*)d_ws;
    float* x      = (float*)w; w += (size_t)N * HID * 4;
    float* xl     = (float*)w; w += (size_t)N * HID * 4;
    float* xr     = (float*)w; w += (size_t)N * HID * 4;
    float* logits = (float*)w; w += (size_t)E * HEADS * 4;
    int*   counts = (int*)w;   w += (size_t)N * 4;
    int*   rowptr = (int*)w;   w += (size_t)(N + 1) * 4;
    int*   nextp  = (int*)w;   w += (size_t)N * 4;
    int*   csr_src= (int*)w;   w += (size_t)E * 4;
    int*   csr_dst= (int*)w;   w += (size_t)E * 4;
    float* psum   = (float*)w; w += (size_t)256 * HID * 4;
    float* pmax   = (float*)w; w += (size_t)256 * HID * 4;

    // CSR build (graph is identical every call; rebuilt each launch as required)
    k_zero_int<<<(N + 255) / 256, 256, 0, stream>>>(counts, N);
    k_hist<<<(E + 255) / 256, 256, 0, stream>>>(dst, E, counts);
    k_scan<<<1, 256, 0, stream>>>(counts, N, rowptr, nextp);
    k_scatter<<<(E + 255) / 256, 256, 0, stream>>>(src, dst, E, nextp, csr_src, csr_dst);

    // embedding
    k_embed<<<N, 128, 0, stream>>>(nf, W_emb, b_emb, x, N);

    for (int i = 0; i < 4; i++) {
        k_linear<<<N, 128, 0, stream>>>(x, Wl + (size_t)i * HID * HID, bl + i * HID,
                                        Wr + (size_t)i * HID * HID, br + i * HID, xl, xr, N);
        int th = E * HEADS;
        k_logits<<<(th + 255) / 256, 256, 0, stream>>>(xl, xr, csr_src, csr_dst,
                                                       att + i * HEADS * CPH, logits, E);
        float* dest = (i == 3) ? xout : x;
        k_aggregate<<<N, 128, 0, stream>>>(xl, logits, rowptr, csr_src,
                                           bias + i * HID, x, dest, i > 0 ? 1 : 0, N);
    }

    k_reduce1<<<256, 128, 0, stream>>>(xout, N, psum, pmax);
    k_reduce2<<<1, 128, 0, stream>>>(psum, pmax, 256, out, 1.0f / N);
}

// Round 2
// 2384.506 us; speedup vs baseline: 2.1623x; 2.1623x over previous
//
#include <hip/hip_runtime.h>
#include <math.h>

#define HID 128
#define HEADS 4
#define CPH 32
#define NEG_SLOPE 0.2f

// ---------------- CSR build ----------------

__global__ __launch_bounds__(256) void k_zero_int(int* p, int n) {
    int i = blockIdx.x * blockDim.x + threadIdx.x;
    if (i < n) p[i] = 0;
}

__global__ __launch_bounds__(256) void k_hist(const int* __restrict__ dst, int E, int* __restrict__ counts) {
    int e = blockIdx.x * blockDim.x + threadIdx.x;
    if (e < E) atomicAdd(&counts[dst[e]], 1);
}

// Single-block exclusive scan over counts[0..N) -> rowptr[0..N]; nextp = rowptr copy.
__global__ __launch_bounds__(256) void k_scan(const int* __restrict__ counts, int N,
                                              int* __restrict__ rowptr, int* __restrict__ nextp) {
    __shared__ int buf[256];
    __shared__ int carry;
    int tid = threadIdx.x;
    if (tid == 0) carry = 0;
    __syncthreads();
    for (int base = 0; base < N; base += 256) {
        int i = base + tid;
        int v = (i < N) ? counts[i] : 0;
        buf[tid] = v;
        __syncthreads();
        for (int off = 1; off < 256; off <<= 1) {
            int t = (tid >= off) ? buf[tid - off] : 0;
            __syncthreads();
            buf[tid] += t;
            __syncthreads();
        }
        int excl = carry + buf[tid] - v;
        if (i < N) { rowptr[i] = excl; nextp[i] = excl; }
        __syncthreads();
        if (tid == 255) carry += buf[255];
        __syncthreads();
    }
    if (tid == 0) rowptr[N] = carry;
}

__global__ __launch_bounds__(256) void k_scatter(const int* __restrict__ src, const int* __restrict__ dst, int E,
                                                 int* __restrict__ nextp,
                                                 int* __restrict__ csr_src, int* __restrict__ csr_dst) {
    int e = blockIdx.x * blockDim.x + threadIdx.x;
    if (e < E) {
        int d = dst[e];
        int pos = atomicAdd(&nextp[d], 1);
        csr_src[pos] = src[e];
        csr_dst[pos] = d;
    }
}

// ---------------- Embedding: x = relu(nf @ W_emb.T + b_emb) ----------------

__global__ __launch_bounds__(128) void k_embed(const float* __restrict__ nf, const float* __restrict__ W,
                                               const float* __restrict__ b, float* __restrict__ x, int N) {
    __shared__ float f[11];
    int n = blockIdx.x;
    int h = threadIdx.x;
    if (h < 11) f[h] = nf[(size_t)n * 11 + h];
    __syncthreads();
    float acc = b[h];
    #pragma unroll
    for (int k = 0; k < 11; k++) acc += f[k] * W[h * 11 + k];
    x[(size_t)n * HID + h] = fmaxf(acc, 0.f);
}

// ---------------- Tiled linear GEMM: xl = x@Wl.T+bl ; xr = x@Wr.T+br ----------------
// grid: (ceil(N/64), 4). blockIdx.y in {0,1} -> xl rows [0:64)/[64:128);
//                        blockIdx.y in {2,3} -> xr rows [0:64)/[64:128).
// Block tile: 64 nodes x 64 outputs; thread tile 4x4; x staged in LDS
// (pad 132: stride-4 row access -> 2-way bank aliasing = free; 528B row
//  stride keeps ds_read_b128 16B-aligned). W from global (L1/L2 resident,
// broadcast across the 4 node-group lanes).

#define BN 64
#define LDX 132

__global__ __launch_bounds__(256) void k_linear(const float* __restrict__ x,
                                                const float* __restrict__ Wl, const float* __restrict__ bl,
                                                const float* __restrict__ Wr, const float* __restrict__ br,
                                                float* __restrict__ xl, float* __restrict__ xr, int N) {
    __shared__ float xs[BN * LDX];
    const int t  = threadIdx.x;
    const int tx = t & 15;         // output group (16)
    const int ty = t >> 4;         // node group (16)
    const int n0 = blockIdx.x * BN;
    const int ob = blockIdx.y;

    // cooperative load of x tile: 64 rows x 32 float4
    for (int i = t; i < BN * 32; i += 256) {
        int r = i >> 5, c = i & 31;
        int n = n0 + r;
        float4 v = (n < N) ? ((const float4*)(x + (size_t)n * HID))[c]
                           : make_float4(0.f, 0.f, 0.f, 0.f);
        *(float4*)&xs[r * LDX + c * 4] = v;
    }
    __syncthreads();

    const float* Wbase = (ob < 2) ? Wl : Wr;
    const int orow0 = (ob & 1) * 64 + tx * 4;   // W row of this thread's first output
    const float4* w4_0 = (const float4*)(Wbase + (size_t)(orow0 + 0) * HID);
    const float4* w4_1 = (const float4*)(Wbase + (size_t)(orow0 + 1) * HID);
    const float4* w4_2 = (const float4*)(Wbase + (size_t)(orow0 + 2) * HID);
    const float4* w4_3 = (const float4*)(Wbase + (size_t)(orow0 + 3) * HID);
    const float* xrow = &xs[(ty * 4) * LDX];

    float acc[4][4];
    #pragma unroll
    for (int i = 0; i < 4; i++)
        #pragma unroll
        for (int j = 0; j < 4; j++) acc[i][j] = 0.f;

    #pragma unroll 4
    for (int k4 = 0; k4 < 32; k4++) {
        float4 xv0 = *(const float4*)&xrow[0 * LDX + k4 * 4];
        float4 xv1 = *(const float4*)&xrow[1 * LDX + k4 * 4];
        float4 xv2 = *(const float4*)&xrow[2 * LDX + k4 * 4];
        float4 xv3 = *(const float4*)&xrow[3 * LDX + k4 * 4];
        float4 wv0 = w4_0[k4];
        float4 wv1 = w4_1[k4];
        float4 wv2 = w4_2[k4];
        float4 wv3 = w4_3[k4];
        float4 xv[4] = {xv0, xv1, xv2, xv3};
        float4 wv[4] = {wv0, wv1, wv2, wv3};
        #pragma unroll
        for (int i = 0; i < 4; i++)
            #pragma unroll
            for (int j = 0; j < 4; j++)
                acc[i][j] += xv[i].x * wv[j].x + xv[i].y * wv[j].y +
                             xv[i].z * wv[j].z + xv[i].w * wv[j].w;
    }

    const float* bvec = (ob < 2) ? bl : br;
    float4 bias4 = *(const float4*)(bvec + orow0);
    float* dstbuf = (ob < 2) ? xl : xr;
    const int ocol = orow0;  // column within the 128-wide output row
    #pragma unroll
    for (int i = 0; i < 4; i++) {
        int n = n0 + ty * 4 + i;
        if (n < N) {
            float4 v = make_float4(acc[i][0] + bias4.x, acc[i][1] + bias4.y,
                                   acc[i][2] + bias4.z, acc[i][3] + bias4.w);
            *(float4*)(dstbuf + (size_t)n * HID + ocol) = v;
        }
    }
}

// ---------------- Edge logits (CSR order): leaky_relu(xl[src]+xr[dst]) . att ----------------

__global__ __launch_bounds__(256) void k_logits(const float* __restrict__ xl, const float* __restrict__ xr,
                                                const int* __restrict__ csr_src, const int* __restrict__ csr_dst,
                                                const float* __restrict__ att, float* __restrict__ logits, int E) {
    int t = blockIdx.x * blockDim.x + threadIdx.x;
    if (t >= E * HEADS) return;
    int j = t >> 2;
    int h = t & 3;
    int s = csr_src[j], d = csr_dst[j];
    const float4* a4 = (const float4*)(xl + (size_t)s * HID + h * CPH);
    const float4* b4 = (const float4*)(xr + (size_t)d * HID + h * CPH);
    const float4* t4 = (const float4*)(att + h * CPH);
    float acc = 0.f;
    #pragma unroll
    for (int q = 0; q < CPH / 4; q++) {
        float4 av = a4[q], bv = b4[q], tv = t4[q];
        float e0 = av.x + bv.x, e1 = av.y + bv.y, e2 = av.z + bv.z, e3 = av.w + bv.w;
        e0 = e0 > 0.f ? e0 : NEG_SLOPE * e0;
        e1 = e1 > 0.f ? e1 : NEG_SLOPE * e1;
        e2 = e2 > 0.f ? e2 : NEG_SLOPE * e2;
        e3 = e3 > 0.f ? e3 : NEG_SLOPE * e3;
        acc += e0 * tv.x + e1 * tv.y + e2 * tv.z + e3 * tv.w;
    }
    logits[t] = acc;
}

// ---------------- Per-node fused softmax + aggregate + bias + relu + residual ----------------

__global__ __launch_bounds__(128) void k_aggregate(const float* __restrict__ xl, const float* __restrict__ logits,
                                                   const int* __restrict__ rowptr, const int* __restrict__ csr_src,
                                                   const float* __restrict__ bias, const float* __restrict__ x_res,
                                                   float* __restrict__ out, int add_res, int N) {
    int n = blockIdx.x;
    int tid = threadIdx.x;
    int h = tid >> 5;
    int c = tid & 31;
    int s0 = rowptr[n], s1 = rowptr[n + 1];
    float mx = -INFINITY;
    for (int j = s0; j < s1; j++) mx = fmaxf(mx, logits[j * 4 + h]);
    float denom = 0.f, acc = 0.f;
    for (int j = s0; j < s1; j++) {
        float p = __expf(logits[j * 4 + h] - mx);
        denom += p;
        acc += p * xl[(size_t)csr_src[j] * HID + h * CPH + c];
    }
    float v = (denom > 0.f) ? acc / denom : 0.f;
    v += bias[tid];
    v = fmaxf(v, 0.f);
    if (add_res) v += x_res[(size_t)n * HID + tid];
    out[(size_t)n * HID + tid] = v;
}

// ---------------- Graph readout: mean + max over nodes ----------------

__global__ __launch_bounds__(128) void k_reduce1(const float* __restrict__ x, int N,
                                                 float* __restrict__ psum, float* __restrict__ pmax) {
    int b = blockIdx.x;
    int h = threadIdx.x;
    int per = (N + gridDim.x - 1) / gridDim.x;
    int n0 = b * per, n1 = min(N, n0 + per);
    float s = 0.f, m = -INFINITY;
    for (int n = n0; n < n1; n++) {
        float v = x[(size_t)n * HID + h];
        s += v;
        m = fmaxf(m, v);
    }
    psum[b * HID + h] = s;
    pmax[b * HID + h] = m;
}

__global__ __launch_bounds__(128) void k_reduce2(const float* __restrict__ psum, const float* __restrict__ pmax,
                                                 int nb, float* __restrict__ out, float invN) {
    int h = threadIdx.x;
    float s = 0.f, m = -INFINITY;
    for (int b = 0; b < nb; b++) {
        s += psum[b * HID + h];
        m = fmaxf(m, pmax[b * HID + h]);
    }
    out[h] = s * invN;
    out[HID + h] = m;
}

// ---------------- Launch ----------------

extern "C" void kernel_launch(void* const* d_in, const int* in_sizes, int n_in,
                              void* d_out, int out_size, void* d_ws, size_t ws_size,
                              hipStream_t stream) {
    const float* nf    = (const float*)d_in[0];
    const int*   ei    = (const int*)d_in[1];
    const float* W_emb = (const float*)d_in[3];
    const float* b_emb = (const float*)d_in[4];
    const float* Wl    = (const float*)d_in[5];
    const float* bl    = (const float*)d_in[6];
    const float* Wr    = (const float*)d_in[7];
    const float* br    = (const float*)d_in[8];
    const float* att   = (const float*)d_in[9];
    const float* bias  = (const float*)d_in[10];

    const int N = in_sizes[0] / 11;
    const int E = in_sizes[1] / 2;
    const int* src = ei;
    const int* dst = ei + E;

    float* out  = (float*)d_out;
    float* xout = out + 2 * HID;  // final per-node features live directly in d_out

    // workspace carve-up
    char* w = (char*)d_ws;
    float* x      = (float*)w; w += (size_t)N * HID * 4;
    float* xl     = (float*)w; w += (size_t)N * HID * 4;
    float* xr     = (float*)w; w += (size_t)N * HID * 4;
    float* logits = (float*)w; w += (size_t)E * HEADS * 4;
    int*   counts = (int*)w;   w += (size_t)N * 4;
    int*   rowptr = (int*)w;   w += (size_t)(N + 1) * 4;
    int*   nextp  = (int*)w;   w += (size_t)N * 4;
    int*   csr_src= (int*)w;   w += (size_t)E * 4;
    int*   csr_dst= (int*)w;   w += (size_t)E * 4;
    float* psum   = (float*)w; w += (size_t)256 * HID * 4;
    float* pmax   = (float*)w; w += (size_t)256 * HID * 4;

    // CSR build (graph is identical every call; rebuilt each launch as required)
    k_zero_int<<<(N + 255) / 256, 256, 0, stream>>>(counts, N);
    k_hist<<<(E + 255) / 256, 256, 0, stream>>>(dst, E, counts);
    k_scan<<<1, 256, 0, stream>>>(counts, N, rowptr, nextp);
    k_scatter<<<(E + 255) / 256, 256, 0, stream>>>(src, dst, E, nextp, csr_src, csr_dst);

    // embedding
    k_embed<<<N, 128, 0, stream>>>(nf, W_emb, b_emb, x, N);

    dim3 lgrid((N + BN - 1) / BN, 4);
    for (int i = 0; i < 4; i++) {
        k_linear<<<lgrid, 256, 0, stream>>>(x, Wl + (size_t)i * HID * HID, bl + i * HID,
                                            Wr + (size_t)i * HID * HID, br + i * HID, xl, xr, N);
        int th = E * HEADS;
        k_logits<<<(th + 255) / 256, 256, 0, stream>>>(xl, xr, csr_src, csr_dst,
                                                       att + i * HEADS * CPH, logits, E);
        float* dest = (i == 3) ? xout : x;
        k_aggregate<<<N, 128, 0, stream>>>(xl, logits, rowptr, csr_src,
                                           bias + i * HID, x, dest, i > 0 ? 1 : 0, N);
    }

    k_reduce1<<<256, 128, 0, stream>>>(xout, N, psum, pmax);
    k_reduce2<<<1, 128, 0, stream>>>(psum, pmax, 256, out, 1.0f / N);
}

// Round 3
// 1816.270 us; speedup vs baseline: 2.8388x; 1.3129x over previous
//
#include <hip/hip_runtime.h>
#include <math.h>

#define HID 128
#define HEADS 4
#define CPH 32
#define NEG_SLOPE 0.2f

// ---------------- CSR build ----------------

__global__ __launch_bounds__(256) void k_zero_int(int* p, int n) {
    int i = blockIdx.x * blockDim.x + threadIdx.x;
    if (i < n) p[i] = 0;
}

__global__ __launch_bounds__(256) void k_hist(const int* __restrict__ dst, int E, int* __restrict__ counts) {
    int e = blockIdx.x * blockDim.x + threadIdx.x;
    if (e < E) atomicAdd(&counts[dst[e]], 1);
}

// Multi-block scan, phase 1: per-block exclusive scan + block partial sum.
__global__ __launch_bounds__(256) void k_scan_block(const int* __restrict__ counts, int N,
                                                    int* __restrict__ scanout, int* __restrict__ partials) {
    __shared__ int buf[256];
    int tid = threadIdx.x;
    int i = blockIdx.x * 256 + tid;
    int v = (i < N) ? counts[i] : 0;
    buf[tid] = v;
    __syncthreads();
    for (int off = 1; off < 256; off <<= 1) {
        int t = (tid >= off) ? buf[tid - off] : 0;
        __syncthreads();
        buf[tid] += t;
        __syncthreads();
    }
    if (i < N) scanout[i] = buf[tid] - v;      // exclusive within block
    if (tid == 255) partials[blockIdx.x] = buf[255];
}

// Phase 2: single block scans the (<=256) block partials into exclusive offsets.
__global__ __launch_bounds__(256) void k_scan_part(int* __restrict__ partials, int nb) {
    __shared__ int buf[256];
    int tid = threadIdx.x;
    int v = (tid < nb) ? partials[tid] : 0;
    buf[tid] = v;
    __syncthreads();
    for (int off = 1; off < 256; off <<= 1) {
        int t = (tid >= off) ? buf[tid - off] : 0;
        __syncthreads();
        buf[tid] += t;
        __syncthreads();
    }
    if (tid < nb) partials[tid] = buf[tid] - v;  // exclusive
}

// Phase 3: add block offsets; emit rowptr and nextp; set rowptr[N]=E.
__global__ __launch_bounds__(256) void k_scan_add(const int* __restrict__ scanout, const int* __restrict__ partials,
                                                  int N, int E, int* __restrict__ rowptr, int* __restrict__ nextp) {
    int i = blockIdx.x * 256 + threadIdx.x;
    if (i < N) {
        int r = scanout[i] + partials[blockIdx.x];
        rowptr[i] = r;
        nextp[i] = r;
    }
    if (i == 0) rowptr[N] = E;
}

__global__ __launch_bounds__(256) void k_scatter(const int* __restrict__ src, const int* __restrict__ dst, int E,
                                                 int* __restrict__ nextp, int* __restrict__ csr_src) {
    int e = blockIdx.x * blockDim.x + threadIdx.x;
    if (e < E) {
        int d = dst[e];
        int pos = atomicAdd(&nextp[d], 1);
        csr_src[pos] = src[e];
    }
}

// ---------------- Embedding: x = relu(nf @ W_emb.T + b_emb) ----------------

__global__ __launch_bounds__(128) void k_embed(const float* __restrict__ nf, const float* __restrict__ W,
                                               const float* __restrict__ b, float* __restrict__ x, int N) {
    __shared__ float f[11];
    int n = blockIdx.x;
    int h = threadIdx.x;
    if (h < 11) f[h] = nf[(size_t)n * 11 + h];
    __syncthreads();
    float acc = b[h];
    #pragma unroll
    for (int k = 0; k < 11; k++) acc += f[k] * W[h * 11 + k];
    x[(size_t)n * HID + h] = fmaxf(acc, 0.f);
}

// ---------------- Tiled linear GEMM: xl = x@Wl.T+bl ; xr = x@Wr.T+br ----------------

#define BN 64
#define LDX 132

__global__ __launch_bounds__(256) void k_linear(const float* __restrict__ x,
                                                const float* __restrict__ Wl, const float* __restrict__ bl,
                                                const float* __restrict__ Wr, const float* __restrict__ br,
                                                float* __restrict__ xl, float* __restrict__ xr, int N) {
    __shared__ float xs[BN * LDX];
    const int t  = threadIdx.x;
    const int tx = t & 15;         // output group (16)
    const int ty = t >> 4;         // node group (16)
    const int n0 = blockIdx.x * BN;
    const int ob = blockIdx.y;

    for (int i = t; i < BN * 32; i += 256) {
        int r = i >> 5, c = i & 31;
        int n = n0 + r;
        float4 v = (n < N) ? ((const float4*)(x + (size_t)n * HID))[c]
                           : make_float4(0.f, 0.f, 0.f, 0.f);
        *(float4*)&xs[r * LDX + c * 4] = v;
    }
    __syncthreads();

    const float* Wbase = (ob < 2) ? Wl : Wr;
    const int orow0 = (ob & 1) * 64 + tx * 4;
    const float4* w4_0 = (const float4*)(Wbase + (size_t)(orow0 + 0) * HID);
    const float4* w4_1 = (const float4*)(Wbase + (size_t)(orow0 + 1) * HID);
    const float4* w4_2 = (const float4*)(Wbase + (size_t)(orow0 + 2) * HID);
    const float4* w4_3 = (const float4*)(Wbase + (size_t)(orow0 + 3) * HID);
    const float* xrow = &xs[(ty * 4) * LDX];

    float acc[4][4];
    #pragma unroll
    for (int i = 0; i < 4; i++)
        #pragma unroll
        for (int j = 0; j < 4; j++) acc[i][j] = 0.f;

    #pragma unroll 4
    for (int k4 = 0; k4 < 32; k4++) {
        float4 xv[4], wv[4];
        xv[0] = *(const float4*)&xrow[0 * LDX + k4 * 4];
        xv[1] = *(const float4*)&xrow[1 * LDX + k4 * 4];
        xv[2] = *(const float4*)&xrow[2 * LDX + k4 * 4];
        xv[3] = *(const float4*)&xrow[3 * LDX + k4 * 4];
        wv[0] = w4_0[k4];
        wv[1] = w4_1[k4];
        wv[2] = w4_2[k4];
        wv[3] = w4_3[k4];
        #pragma unroll
        for (int i = 0; i < 4; i++)
            #pragma unroll
            for (int j = 0; j < 4; j++)
                acc[i][j] += xv[i].x * wv[j].x + xv[i].y * wv[j].y +
                             xv[i].z * wv[j].z + xv[i].w * wv[j].w;
    }

    const float* bvec = (ob < 2) ? bl : br;
    float4 bias4 = *(const float4*)(bvec + orow0);
    float* dstbuf = (ob < 2) ? xl : xr;
    #pragma unroll
    for (int i = 0; i < 4; i++) {
        int n = n0 + ty * 4 + i;
        if (n < N) {
            float4 v = make_float4(acc[i][0] + bias4.x, acc[i][1] + bias4.y,
                                   acc[i][2] + bias4.z, acc[i][3] + bias4.w);
            *(float4*)(dstbuf + (size_t)n * HID + orow0) = v;
        }
    }
}

// ---------------- Fused attention: logits + online softmax + aggregate + epilogue ----------------
// 2 nodes per 256-thread block; each 128-thread half owns one node.
// Per edge: gather xl[src] row (coalesced 512B, prefetched), compute head
// logit via width-32 shuffle reduction, online-softmax update of (m, denom, acc).

__global__ __launch_bounds__(256) void k_attn(const float* __restrict__ xl, const float* __restrict__ xr,
                                              const int* __restrict__ rowptr, const int* __restrict__ csr_src,
                                              const float* __restrict__ att, const float* __restrict__ bias,
                                              const float* __restrict__ x_res, float* __restrict__ out,
                                              int add_res, int N) {
    const int half = threadIdx.x >> 7;
    const int tid  = threadIdx.x & 127;   // channel within node (h = tid>>5, c = tid&31)
    const int n = blockIdx.x * 2 + half;
    if (n >= N) return;

    const float a   = att[tid];                       // att[h*32+c]
    const float xrv = xr[(size_t)n * HID + tid];
    const int s0 = rowptr[n], s1 = rowptr[n + 1];

    float m = -INFINITY, denom = 0.f, acc = 0.f;

    // software prefetch of the first edge's xl row
    float xlv = 0.f;
    if (s0 < s1) {
        int sj = csr_src[s0];
        xlv = xl[(size_t)sj * HID + tid];
    }
    for (int j = s0; j < s1; j++) {
        float cur = xlv;
        if (j + 1 < s1) {
            int sn = csr_src[j + 1];
            xlv = xl[(size_t)sn * HID + tid];   // prefetch next edge
        }
        float e = cur + xrv;
        e = e > 0.f ? e : NEG_SLOPE * e;
        float p = e * a;
        p += __shfl_xor(p, 16, 32);
        p += __shfl_xor(p, 8, 32);
        p += __shfl_xor(p, 4, 32);
        p += __shfl_xor(p, 2, 32);
        p += __shfl_xor(p, 1, 32);              // head logit, on all 32 lanes
        float nm = fmaxf(m, p);
        float scale = __expf(m - nm);
        float w = __expf(p - nm);
        denom = denom * scale + w;
        acc   = acc * scale + w * cur;
        m = nm;
    }

    float v = (denom > 0.f) ? acc / denom : 0.f;
    v += bias[tid];
    v = fmaxf(v, 0.f);
    if (add_res) v += x_res[(size_t)n * HID + tid];
    out[(size_t)n * HID + tid] = v;
}

// ---------------- Graph readout: mean + max over nodes ----------------

__global__ __launch_bounds__(128) void k_reduce1(const float* __restrict__ x, int N,
                                                 float* __restrict__ psum, float* __restrict__ pmax) {
    int b = blockIdx.x;
    int h = threadIdx.x;
    int per = (N + gridDim.x - 1) / gridDim.x;
    int n0 = b * per, n1 = min(N, n0 + per);
    float s = 0.f, m = -INFINITY;
    for (int n = n0; n < n1; n++) {
        float v = x[(size_t)n * HID + h];
        s += v;
        m = fmaxf(m, v);
    }
    psum[b * HID + h] = s;
    pmax[b * HID + h] = m;
}

__global__ __launch_bounds__(128) void k_reduce2(const float* __restrict__ psum, const float* __restrict__ pmax,
                                                 int nb, float* __restrict__ out, float invN) {
    int h = threadIdx.x;
    float s = 0.f, m = -INFINITY;
    for (int b = 0; b < nb; b++) {
        s += psum[b * HID + h];
        m = fmaxf(m, pmax[b * HID + h]);
    }
    out[h] = s * invN;
    out[HID + h] = m;
}

// ---------------- Launch ----------------

extern "C" void kernel_launch(void* const* d_in, const int* in_sizes, int n_in,
                              void* d_out, int out_size, void* d_ws, size_t ws_size,
                              hipStream_t stream) {
    const float* nf    = (const float*)d_in[0];
    const int*   ei    = (const int*)d_in[1];
    const float* W_emb = (const float*)d_in[3];
    const float* b_emb = (const float*)d_in[4];
    const float* Wl    = (const float*)d_in[5];
    const float* bl    = (const float*)d_in[6];
    const float* Wr    = (const float*)d_in[7];
    const float* br    = (const float*)d_in[8];
    const float* att   = (const float*)d_in[9];
    const float* bias  = (const float*)d_in[10];

    const int N = in_sizes[0] / 11;
    const int E = in_sizes[1] / 2;
    const int* src = ei;
    const int* dst = ei + E;

    float* out  = (float*)d_out;
    float* xout = out + 2 * HID;  // final per-node features live directly in d_out

    // workspace carve-up
    char* w = (char*)d_ws;
    float* x       = (float*)w; w += (size_t)N * HID * 4;
    float* xl      = (float*)w; w += (size_t)N * HID * 4;
    float* xr      = (float*)w; w += (size_t)N * HID * 4;
    int*   counts  = (int*)w;   w += (size_t)N * 4;
    int*   scanout = (int*)w;   w += (size_t)N * 4;
    int*   rowptr  = (int*)w;   w += (size_t)(N + 1) * 4;
    int*   nextp   = (int*)w;   w += (size_t)N * 4;
    int*   partials= (int*)w;   w += (size_t)256 * 4;
    int*   csr_src = (int*)w;   w += (size_t)E * 4;
    float* psum    = (float*)w; w += (size_t)256 * HID * 4;
    float* pmax    = (float*)w; w += (size_t)256 * HID * 4;

    const int nb = (N + 255) / 256;

    // CSR build
    k_zero_int<<<nb, 256, 0, stream>>>(counts, N);
    k_hist<<<(E + 255) / 256, 256, 0, stream>>>(dst, E, counts);
    k_scan_block<<<nb, 256, 0, stream>>>(counts, N, scanout, partials);
    k_scan_part<<<1, 256, 0, stream>>>(partials, nb);
    k_scan_add<<<nb, 256, 0, stream>>>(scanout, partials, N, E, rowptr, nextp);
    k_scatter<<<(E + 255) / 256, 256, 0, stream>>>(src, dst, E, nextp, csr_src);

    // embedding
    k_embed<<<N, 128, 0, stream>>>(nf, W_emb, b_emb, x, N);

    dim3 lgrid((N + BN - 1) / BN, 4);
    for (int i = 0; i < 4; i++) {
        k_linear<<<lgrid, 256, 0, stream>>>(x, Wl + (size_t)i * HID * HID, bl + i * HID,
                                            Wr + (size_t)i * HID * HID, br + i * HID, xl, xr, N);
        float* dest = (i == 3) ? xout : x;
        k_attn<<<(N + 1) / 2, 256, 0, stream>>>(xl, xr, rowptr, csr_src,
                                                att + i * HEADS * CPH, bias + i * HID,
                                                x, dest, i > 0 ? 1 : 0, N);
    }

    k_reduce1<<<256, 128, 0, stream>>>(xout, N, psum, pmax);
    k_reduce2<<<1, 128, 0, stream>>>(psum, pmax, 256, out, 1.0f / N);
}

// Round 4
// 878.916 us; speedup vs baseline: 5.8664x; 2.0665x over previous
//
#include <hip/hip_runtime.h>
#include <math.h>

#define HID 128
#define HEADS 4
#define NEG_SLOPE 0.2f

typedef short bf16x8 __attribute__((ext_vector_type(8)));   // 8 bf16 in 4 VGPRs
typedef float f32x4 __attribute__((ext_vector_type(4)));

// ---------------- CSR build ----------------

__global__ __launch_bounds__(256) void k_zero_int(int* p, int n) {
    int i = blockIdx.x * blockDim.x + threadIdx.x;
    if (i < n) p[i] = 0;
}

__global__ __launch_bounds__(256) void k_hist(const int* __restrict__ dst, int E, int* __restrict__ counts) {
    int e = blockIdx.x * blockDim.x + threadIdx.x;
    if (e < E) atomicAdd(&counts[dst[e]], 1);
}

__global__ __launch_bounds__(256) void k_scan_block(const int* __restrict__ counts, int N,
                                                    int* __restrict__ scanout, int* __restrict__ partials) {
    __shared__ int buf[256];
    int tid = threadIdx.x;
    int i = blockIdx.x * 256 + tid;
    int v = (i < N) ? counts[i] : 0;
    buf[tid] = v;
    __syncthreads();
    for (int off = 1; off < 256; off <<= 1) {
        int t = (tid >= off) ? buf[tid - off] : 0;
        __syncthreads();
        buf[tid] += t;
        __syncthreads();
    }
    if (i < N) scanout[i] = buf[tid] - v;
    if (tid == 255) partials[blockIdx.x] = buf[255];
}

__global__ __launch_bounds__(256) void k_scan_part(int* __restrict__ partials, int nb) {
    __shared__ int buf[256];
    int tid = threadIdx.x;
    int v = (tid < nb) ? partials[tid] : 0;
    buf[tid] = v;
    __syncthreads();
    for (int off = 1; off < 256; off <<= 1) {
        int t = (tid >= off) ? buf[tid - off] : 0;
        __syncthreads();
        buf[tid] += t;
        __syncthreads();
    }
    if (tid < nb) partials[tid] = buf[tid] - v;
}

__global__ __launch_bounds__(256) void k_scan_add(const int* __restrict__ scanout, const int* __restrict__ partials,
                                                  int N, int E, int* __restrict__ rowptr, int* __restrict__ nextp) {
    int i = blockIdx.x * 256 + threadIdx.x;
    if (i < N) {
        int r = scanout[i] + partials[blockIdx.x];
        rowptr[i] = r;
        nextp[i] = r;
    }
    if (i == 0) rowptr[N] = E;
}

__global__ __launch_bounds__(256) void k_scatter(const int* __restrict__ src, const int* __restrict__ dst, int E,
                                                 int* __restrict__ nextp, int* __restrict__ csr_src) {
    int e = blockIdx.x * blockDim.x + threadIdx.x;
    if (e < E) {
        int d = dst[e];
        int pos = atomicAdd(&nextp[d], 1);
        csr_src[pos] = src[e];
    }
}

// ---------------- fp32 -> bf16 (hi, lo) split ----------------

__device__ inline unsigned short f2bf(float f) {
    unsigned u = __float_as_uint(f);
    unsigned r = (u + 0x7FFF + ((u >> 16) & 1)) >> 16;
    return (unsigned short)r;
}

__global__ __launch_bounds__(256) void k_tobf16(const float* __restrict__ x,
                                                unsigned short* __restrict__ hi,
                                                unsigned short* __restrict__ lo, int n) {
    int i = blockIdx.x * 256 + threadIdx.x;
    int base = i * 4;
    if (base >= n) return;
    float4 v = *(const float4*)(x + base);
    float f[4] = {v.x, v.y, v.z, v.w};
    ushort4 h, l;
    unsigned short hh[4], ll[4];
    #pragma unroll
    for (int q = 0; q < 4; q++) {
        unsigned short a = f2bf(f[q]);
        hh[q] = a;
        float rec = __uint_as_float(((unsigned)a) << 16);
        ll[q] = f2bf(f[q] - rec);
    }
    h.x = hh[0]; h.y = hh[1]; h.z = hh[2]; h.w = hh[3];
    l.x = ll[0]; l.y = ll[1]; l.z = ll[2]; l.w = ll[3];
    *(ushort4*)(hi + base) = h;
    *(ushort4*)(lo + base) = l;
}

// ---------------- MFMA linear: xl = x@Wl.T+bl ; xr = x@Wr.T+br ----------------
// Split-precision: x*W ~= xh*Wh + xh*Wl + xl*Wh (bf16 MFMA, fp32 accumulate).
// grid (ceil(N/64), 4): y 0/1 -> Wl out-halves, y 2/3 -> Wr out-halves.
// Wave = 16 nodes x 64 outs (4 subtiles of 16x16x32 MFMA).
// A frag: A[m=lane&15][k=quad*8+j]; B frag: W row n=lane&15, k contiguous.
// C/D: col=lane&15, row=quad*4+reg  (verified m89 mapping).

__global__ __launch_bounds__(256) void k_linear_mfma(
        const unsigned short* __restrict__ xhi, const unsigned short* __restrict__ xlo,
        const unsigned short* __restrict__ whiL, const unsigned short* __restrict__ wloL,
        const unsigned short* __restrict__ whiR, const unsigned short* __restrict__ wloR,
        const float* __restrict__ bl, const float* __restrict__ br,
        float* __restrict__ xl, float* __restrict__ xr, int N) {
    const int wave = threadIdx.x >> 6;
    const int lane = threadIdx.x & 63;
    const int l16  = lane & 15;
    const int quad = lane >> 4;
    const int n0   = blockIdx.x * 64 + wave * 16;
    const int ob   = blockIdx.y;
    const int mat  = ob >> 1;          // 0 = Wl, 1 = Wr
    const int out0 = (ob & 1) * 64;

    const unsigned short* Wh = mat ? whiR : whiL;
    const unsigned short* Wo = mat ? wloR : wloL;

    int arow = n0 + l16;
    if (arow >= N) arow = N - 1;       // clamp loads; stores guarded below

    f32x4 acc[4];
    #pragma unroll
    for (int s = 0; s < 4; s++) acc[s] = (f32x4){0.f, 0.f, 0.f, 0.f};

    #pragma unroll
    for (int k0 = 0; k0 < HID; k0 += 32) {
        const int aoff = arow * HID + k0 + quad * 8;
        bf16x8 ahi = *(const bf16x8*)(xhi + aoff);
        bf16x8 alo = *(const bf16x8*)(xlo + aoff);
        #pragma unroll
        for (int s = 0; s < 4; s++) {
            const int boff = (out0 + s * 16 + l16) * HID + k0 + quad * 8;
            bf16x8 bhi = *(const bf16x8*)(Wh + boff);
            bf16x8 blo = *(const bf16x8*)(Wo + boff);
            acc[s] = __builtin_amdgcn_mfma_f32_16x16x32_bf16(ahi, bhi, acc[s], 0, 0, 0);
            acc[s] = __builtin_amdgcn_mfma_f32_16x16x32_bf16(ahi, blo, acc[s], 0, 0, 0);
            acc[s] = __builtin_amdgcn_mfma_f32_16x16x32_bf16(alo, bhi, acc[s], 0, 0, 0);
        }
    }

    float* dst = mat ? xr : xl;
    const float* bias = mat ? br : bl;
    #pragma unroll
    for (int s = 0; s < 4; s++) {
        int col = out0 + s * 16 + l16;
        float bv = bias[col];
        #pragma unroll
        for (int r = 0; r < 4; r++) {
            int node = n0 + quad * 4 + r;
            if (node < N) dst[(size_t)node * HID + col] = acc[s][r] + bv;
        }
    }
}

// ---------------- Fused attention: wave per node, 2 edge streams, online softmax ----------------

__global__ __launch_bounds__(256) void k_attn(const float* __restrict__ xl, const float* __restrict__ xr,
                                              const int* __restrict__ rowptr, const int* __restrict__ csr_src,
                                              const float* __restrict__ att, const float* __restrict__ bias,
                                              const float* __restrict__ x_res, float* __restrict__ out,
                                              int add_res, int N) {
    const int wave = threadIdx.x >> 6;
    const int lane = threadIdx.x & 63;
    const int sub  = lane >> 5;          // edge stream 0/1
    const int l32  = lane & 31;          // channels [4*l32, 4*l32+4); head = l32>>3
    const int n = blockIdx.x * 4 + wave;
    if (n >= N) return;

    const float4 a4  = *(const float4*)(att + 4 * l32);
    const float4 xr4 = *(const float4*)(xr + (size_t)n * HID + 4 * l32);
    const int s0 = rowptr[n], s1 = rowptr[n + 1];

    float m = -INFINITY, den = 0.f;
    float4 acc = make_float4(0.f, 0.f, 0.f, 0.f);

    int j = s0 + sub;
    float4 xlv = make_float4(0.f, 0.f, 0.f, 0.f);
    if (j < s1) xlv = *(const float4*)(xl + (size_t)csr_src[j] * HID + 4 * l32);
    while (j < s1) {
        float4 cur = xlv;
        int jn = j + 2;
        if (jn < s1) xlv = *(const float4*)(xl + (size_t)csr_src[jn] * HID + 4 * l32);
        float e0 = cur.x + xr4.x; e0 = e0 > 0.f ? e0 : NEG_SLOPE * e0;
        float e1 = cur.y + xr4.y; e1 = e1 > 0.f ? e1 : NEG_SLOPE * e1;
        float e2 = cur.z + xr4.z; e2 = e2 > 0.f ? e2 : NEG_SLOPE * e2;
        float e3 = cur.w + xr4.w; e3 = e3 > 0.f ? e3 : NEG_SLOPE * e3;
        float p = e0 * a4.x + e1 * a4.y + e2 * a4.z + e3 * a4.w;
        p += __shfl_xor(p, 1);           // reduce 8-lane head group (low-3 bits)
        p += __shfl_xor(p, 2);
        p += __shfl_xor(p, 4);
        float nm = fmaxf(m, p);
        float sc = __expf(m - nm);
        float w  = __expf(p - nm);
        den = den * sc + w;
        acc.x = acc.x * sc + w * cur.x;
        acc.y = acc.y * sc + w * cur.y;
        acc.z = acc.z * sc + w * cur.z;
        acc.w = acc.w * sc + w * cur.w;
        m = nm;
        j = jn;
    }

    // merge the two streams across the half-wave boundary
    float m2   = __shfl_xor(m, 32);
    float den2 = __shfl_xor(den, 32);
    float4 acc2;
    acc2.x = __shfl_xor(acc.x, 32);
    acc2.y = __shfl_xor(acc.y, 32);
    acc2.z = __shfl_xor(acc.z, 32);
    acc2.w = __shfl_xor(acc.w, 32);
    float nm = fmaxf(m, m2);
    float sA = __expf(m - nm), sB = __expf(m2 - nm);
    den = den * sA + den2 * sB;
    acc.x = acc.x * sA + acc2.x * sB;
    acc.y = acc.y * sA + acc2.y * sB;
    acc.z = acc.z * sA + acc2.z * sB;
    acc.w = acc.w * sA + acc2.w * sB;

    if (sub == 0) {
        float4 b4 = *(const float4*)(bias + 4 * l32);
        float inv = (den > 0.f) ? 1.f / den : 0.f;
        float4 v;
        v.x = fmaxf(acc.x * inv + b4.x, 0.f);
        v.y = fmaxf(acc.y * inv + b4.y, 0.f);
        v.z = fmaxf(acc.z * inv + b4.z, 0.f);
        v.w = fmaxf(acc.w * inv + b4.w, 0.f);
        if (add_res) {
            float4 r4 = *(const float4*)(x_res + (size_t)n * HID + 4 * l32);
            v.x += r4.x; v.y += r4.y; v.z += r4.z; v.w += r4.w;
        }
        *(float4*)(out + (size_t)n * HID + 4 * l32) = v;
    }
}

// ---------------- Embedding: x = relu(nf @ W_emb.T + b_emb) ----------------

__global__ __launch_bounds__(128) void k_embed(const float* __restrict__ nf, const float* __restrict__ W,
                                               const float* __restrict__ b, float* __restrict__ x, int N) {
    __shared__ float f[11];
    int n = blockIdx.x;
    int h = threadIdx.x;
    if (h < 11) f[h] = nf[(size_t)n * 11 + h];
    __syncthreads();
    float acc = b[h];
    #pragma unroll
    for (int k = 0; k < 11; k++) acc += f[k] * W[h * 11 + k];
    x[(size_t)n * HID + h] = fmaxf(acc, 0.f);
}

// ---------------- Graph readout: mean + max over nodes ----------------

__global__ __launch_bounds__(128) void k_reduce1(const float* __restrict__ x, int N,
                                                 float* __restrict__ psum, float* __restrict__ pmax) {
    int b = blockIdx.x;
    int h = threadIdx.x;
    int per = (N + gridDim.x - 1) / gridDim.x;
    int n0 = b * per, n1 = min(N, n0 + per);
    float s = 0.f, m = -INFINITY;
    for (int n = n0; n < n1; n++) {
        float v = x[(size_t)n * HID + h];
        s += v;
        m = fmaxf(m, v);
    }
    psum[b * HID + h] = s;
    pmax[b * HID + h] = m;
}

__global__ __launch_bounds__(128) void k_reduce2(const float* __restrict__ psum, const float* __restrict__ pmax,
                                                 int nb, float* __restrict__ out, float invN) {
    int h = threadIdx.x;
    float s = 0.f, m = -INFINITY;
    for (int b = 0; b < nb; b++) {
        s += psum[b * HID + h];
        m = fmaxf(m, pmax[b * HID + h]);
    }
    out[h] = s * invN;
    out[HID + h] = m;
}

// ---------------- Launch ----------------

extern "C" void kernel_launch(void* const* d_in, const int* in_sizes, int n_in,
                              void* d_out, int out_size, void* d_ws, size_t ws_size,
                              hipStream_t stream) {
    const float* nf    = (const float*)d_in[0];
    const int*   ei    = (const int*)d_in[1];
    const float* W_emb = (const float*)d_in[3];
    const float* b_emb = (const float*)d_in[4];
    const float* Wl    = (const float*)d_in[5];
    const float* bl    = (const float*)d_in[6];
    const float* Wr    = (const float*)d_in[7];
    const float* br    = (const float*)d_in[8];
    const float* att   = (const float*)d_in[9];
    const float* bias  = (const float*)d_in[10];

    const int N = in_sizes[0] / 11;
    const int E = in_sizes[1] / 2;
    const int* src = ei;
    const int* dst = ei + E;

    float* out  = (float*)d_out;
    float* xout = out + 2 * HID;

    // workspace carve-up
    char* w = (char*)d_ws;
    float* x        = (float*)w; w += (size_t)N * HID * 4;
    float* xl       = (float*)w; w += (size_t)N * HID * 4;
    float* xr       = (float*)w; w += (size_t)N * HID * 4;
    unsigned short* xhi = (unsigned short*)w; w += (size_t)N * HID * 2;
    unsigned short* xlo = (unsigned short*)w; w += (size_t)N * HID * 2;
    unsigned short* whiL = (unsigned short*)w; w += (size_t)4 * HID * HID * 2;
    unsigned short* wloL = (unsigned short*)w; w += (size_t)4 * HID * HID * 2;
    unsigned short* whiR = (unsigned short*)w; w += (size_t)4 * HID * HID * 2;
    unsigned short* wloR = (unsigned short*)w; w += (size_t)4 * HID * HID * 2;
    int*   counts   = (int*)w;   w += (size_t)N * 4;
    int*   scanout  = (int*)w;   w += (size_t)N * 4;
    int*   rowptr   = (int*)w;   w += (size_t)(N + 1) * 4;
    int*   nextp    = (int*)w;   w += (size_t)N * 4;
    int*   partials = (int*)w;   w += (size_t)256 * 4;
    int*   csr_src  = (int*)w;   w += (size_t)E * 4;
    float* psum     = (float*)w; w += (size_t)256 * HID * 4;
    float* pmax     = (float*)w; w += (size_t)256 * HID * 4;

    const int nb = (N + 255) / 256;
    const int nW = 4 * HID * HID;

    // weight bf16 split (once per launch)
    k_tobf16<<<(nW / 4 + 255) / 256, 256, 0, stream>>>(Wl, whiL, wloL, nW);
    k_tobf16<<<(nW / 4 + 255) / 256, 256, 0, stream>>>(Wr, whiR, wloR, nW);

    // CSR build
    k_zero_int<<<nb, 256, 0, stream>>>(counts, N);
    k_hist<<<(E + 255) / 256, 256, 0, stream>>>(dst, E, counts);
    k_scan_block<<<nb, 256, 0, stream>>>(counts, N, scanout, partials);
    k_scan_part<<<1, 256, 0, stream>>>(partials, nb);
    k_scan_add<<<nb, 256, 0, stream>>>(scanout, partials, N, E, rowptr, nextp);
    k_scatter<<<(E + 255) / 256, 256, 0, stream>>>(src, dst, E, nextp, csr_src);

    // embedding
    k_embed<<<N, 128, 0, stream>>>(nf, W_emb, b_emb, x, N);

    const int nx = N * HID;
    dim3 lgrid((N + 63) / 64, 4);
    for (int i = 0; i < 4; i++) {
        k_tobf16<<<(nx / 4 + 255) / 256, 256, 0, stream>>>(x, xhi, xlo, nx);
        k_linear_mfma<<<lgrid, 256, 0, stream>>>(xhi, xlo,
                                                 whiL + (size_t)i * HID * HID, wloL + (size_t)i * HID * HID,
                                                 whiR + (size_t)i * HID * HID, wloR + (size_t)i * HID * HID,
                                                 bl + i * HID, br + i * HID, xl, xr, N);
        float* dest = (i == 3) ? xout : x;
        k_attn<<<(N + 3) / 4, 256, 0, stream>>>(xl, xr, rowptr, csr_src,
                                                att + i * HEADS * 32, bias + i * HID,
                                                x, dest, i > 0 ? 1 : 0, N);
    }

    k_reduce1<<<256, 128, 0, stream>>>(xout, N, psum, pmax);
    k_reduce2<<<1, 128, 0, stream>>>(psum, pmax, 256, out, 1.0f / N);
}